// Round 4
// baseline (312.129 us; speedup 1.0000x reference)
//
#include <hip/hip_runtime.h>
#include <hip/hip_bf16.h>
#include <cstddef>
#include <cstdint>

#define B_  8
#define S_  32
#define BT_ 256      // B*S
#define N_  2000
#define E_  64000
#define GH_ 32
#define H_  64
#define G4_ 256      // 4*H
#define D_  64000    // N*GH
#define NEG_SLOPE_ 0.2f

#define KC2_  50     // K-chunks
#define NPC2_ 40     // nodes per chunk (50*40 = 2000)

typedef __attribute__((ext_vector_type(8))) _Float16 half8;
typedef __attribute__((ext_vector_type(4))) float floatx4;

__device__ __forceinline__ float fsigmoid(float x) { return 1.0f / (1.0f + __expf(-x)); }
__device__ __forceinline__ float ftanh_(float x)   { return 1.0f - 2.0f / (__expf(2.0f * x) + 1.0f); }

// ---------------------------------------------------------------------------
// K1: CSR build in ONE block (replaces memset+hist+scan+scatter = 4 dispatches).
// 1024 threads: LDS histogram -> LDS exclusive scan -> LDS-cursor scatter.
// ---------------------------------------------------------------------------
__global__ __launch_bounds__(1024) void csr_build_kernel(
    const int* __restrict__ ei, int* __restrict__ rowptr, int* __restrict__ csr_src)
{
  __shared__ int deg_s[N_];
  __shared__ int cur_s[N_];
  __shared__ int tsum[1024];
  const int tid = threadIdx.x;

  for (int n = tid; n < N_; n += 1024) deg_s[n] = 0;
  __syncthreads();

  for (int i = tid; i < E_; i += 1024) atomicAdd(&deg_s[ei[E_ + i]], 1);
  __syncthreads();

  // exclusive scan of 2000 degrees; thread t owns entries 2t, 2t+1
  const int i0 = tid * 2, i1 = tid * 2 + 1;
  const int d0 = (i0 < N_) ? deg_s[i0] : 0;
  const int d1 = (i1 < N_) ? deg_s[i1] : 0;
  const int sl = d0 + d1;
  tsum[tid] = sl;
  __syncthreads();
  for (int off = 1; off < 1024; off <<= 1) {
    int t = 0;
    if (tid >= off) t = tsum[tid - off];
    __syncthreads();
    tsum[tid] += t;
    __syncthreads();
  }
  const int ebase = tsum[tid] - sl;
  if (i0 < N_) { rowptr[i0] = ebase;      cur_s[i0] = ebase; }
  if (i1 < N_) { rowptr[i1] = ebase + d0; cur_s[i1] = ebase + d0; }
  if (tid == 0) rowptr[N_] = E_;
  __syncthreads();

  for (int i = tid; i < E_; i += 1024) {
    const int s = ei[i];
    const int d = ei[E_ + i];
    const int pos = atomicAdd(&cur_s[d], 1);
    csr_src[pos] = s;
  }
}

// ---------------------------------------------------------------------------
// K2: transpose x [bt][n] -> xT [n][bt], 32x32 LDS tiles
// ---------------------------------------------------------------------------
__global__ __launch_bounds__(256) void transpose_kernel(
    const float* __restrict__ x, float* __restrict__ xT)
{
  __shared__ float tile[32][33];
  const int tx = threadIdx.x & 31;
  const int ty = threadIdx.x >> 5;
  const int n0  = blockIdx.x * 32;
  const int bt0 = blockIdx.y * 32;
#pragma unroll
  for (int r = 0; r < 4; ++r) {
    const int bt = bt0 + ty + r * 8;
    const int nn = n0 + tx;
    if (nn < N_) tile[ty + r * 8][tx] = x[(size_t)bt * N_ + nn];
  }
  __syncthreads();
#pragma unroll
  for (int r = 0; r < 4; ++r) {
    const int n = n0 + ty + r * 8;
    if (n < N_) xT[(size_t)n * BT_ + bt0 + tx] = tile[tx][ty + r * 8];
  }
}

// ---------------------------------------------------------------------------
// K3: gather-aggregate + fp16 A-expansion (fused).
// One block per node n; thread = bt.
// agg = (sum_in exp(e)*x_src + exp(e_self)*x_n) / (sum exp)
// Then write A[n][bt][gh] = (fp16) relu(agg*wl[gh]+gb[gh])  — the lstm_in
// fragment layout the MFMA kernel consumes directly.
// ---------------------------------------------------------------------------
__global__ __launch_bounds__(256) void gat_gather_expand_kernel(
    const float* __restrict__ xT, const int* __restrict__ rowptr,
    const int* __restrict__ csr_src,
    const float* __restrict__ w_lin, const float* __restrict__ att_src,
    const float* __restrict__ att_dst, const float* __restrict__ gat_bias,
    _Float16* __restrict__ A)
{
  __shared__ int srcs[512];
  __shared__ float wl_s[GH_], gb_s[GH_];
  const int n   = blockIdx.x;
  const int tid = threadIdx.x;

  float c_s = 0.f, c_d = 0.f;
  for (int g = 0; g < GH_; ++g) {
    const float w = w_lin[g];
    c_s += w * att_src[g];
    c_d += w * att_dst[g];
  }
  if (tid < GH_) { wl_s[tid] = w_lin[tid]; gb_s[tid] = gat_bias[tid]; }

  const int r0 = rowptr[n];
  const int r1 = rowptr[n + 1];
  const int d  = r1 - r0;
  for (int i = tid; i < d && i < 512; i += 256) srcs[i] = csr_src[r0 + i];
  __syncthreads();

  const float xn = xT[(size_t)n * BT_ + tid];
  float e = (c_s + c_d) * xn;
  e = e > 0.f ? e : NEG_SLOPE_ * e;
  float w = __expf(e);
  float num = w * xn;
  float den = w;

  for (int p = 0; p < d; ++p) {
    int s;
    if (p < 512) s = srcs[p]; else s = csr_src[r0 + p];
    const float xs = xT[(size_t)s * BT_ + tid];
    float ee = c_s * xs + c_d * xn;
    ee = ee > 0.f ? ee : NEG_SLOPE_ * ee;
    const float ww = __expf(ee);
    num += ww * xs;
    den += ww;
  }
  const float aggv = num / den;

  // expand to fp16 lstm_in fragment: 32 values, 64B contiguous per thread
  half8 buf[4];
#pragma unroll
  for (int q = 0; q < 4; ++q)
#pragma unroll
    for (int j = 0; j < 8; ++j) {
      const int g = q * 8 + j;
      float v = fmaf(aggv, wl_s[g], gb_s[g]);
      v = fmaxf(v, 0.f);
      buf[q][j] = (_Float16)v;
    }
  half8* dst = (half8*)(A + ((size_t)n * BT_ + tid) * GH_);
#pragma unroll
  for (int q = 0; q < 4; ++q) dst[q] = buf[q];
}

// ---------------------------------------------------------------------------
// K4: single-pass fp16 MFMA matmul.
// pre_gates[bt, j] = sum_k W_ih[j, k] * A[bt, k], A precomputed fp16.
// Block: M=256 x N=32 (nb=8 gate-blocks); wave: M=64 x N=32 (4x2 16x16 tiles).
// K-chunked: 40 nodes (1280 k) per block; grid = (8, 50) = 400 blocks.
// W_ih read once from HBM (fp32, cvt to fp16 in-flight); A from L2/L3.
// No LDS, no barriers. Split-K partials + separate reduce (atomic fallback).
// ---------------------------------------------------------------------------
__global__ __launch_bounds__(256) void gate_mfma2_kernel(
    const float* __restrict__ W_ih, const _Float16* __restrict__ A,
    float* __restrict__ partial, float* __restrict__ pre_gates, int use_atomic)
{
  const int tid  = threadIdx.x;
  const int nb   = blockIdx.x;     // 0..7
  const int kc   = blockIdx.y;     // 0..49
  const int n0   = kc * NPC2_;
  const int wv   = tid >> 6;
  const int lane = tid & 63;
  const int i16  = lane & 15;
  const int q    = lane >> 4;
  const int jn0  = nb * 32;

  floatx4 acc[4][2];
#pragma unroll
  for (int mt = 0; mt < 4; ++mt)
#pragma unroll
    for (int nt = 0; nt < 2; ++nt)
#pragma unroll
      for (int r = 0; r < 4; ++r) acc[mt][nt][r] = 0.f;

  // A lane pointer: row m = wv*64 + mt*16 + i16, elem offset q*8; advance 8192/node
  const _Float16* Ap = A + ((size_t)n0 * BT_ + wv * 64 + i16) * GH_ + q * 8;

  // B lane pointers: rows j = jn0 + nt*16 + i16, col = n0*32 + q*8
  const float* Bp0 = W_ih + (size_t)(jn0 + i16) * D_ + (size_t)n0 * GH_ + q * 8;
  const float* Bp1 = Bp0 + (size_t)16 * D_;

  float4 b0a = *(const float4*)(Bp0);
  float4 b0b = *(const float4*)(Bp0 + 4);
  float4 b1a = *(const float4*)(Bp1);
  float4 b1b = *(const float4*)(Bp1 + 4);

#pragma unroll 1
  for (int nn = 0; nn < NPC2_; ++nn) {
    // A fragments for this node (L2/L3-hot stream)
    half8 a0 = *(const half8*)(Ap + 0 * 512);
    half8 a1 = *(const half8*)(Ap + 1 * 512);
    half8 a2 = *(const half8*)(Ap + 2 * 512);
    half8 a3 = *(const half8*)(Ap + 3 * 512);

    // prefetch next node's B (clamped at the tail to avoid OOB)
    const int nx = (nn + 1 < NPC2_) ? (nn + 1) : nn;
    float4 p0a = *(const float4*)(Bp0 + nx * GH_);
    float4 p0b = *(const float4*)(Bp0 + nx * GH_ + 4);
    float4 p1a = *(const float4*)(Bp1 + nx * GH_);
    float4 p1b = *(const float4*)(Bp1 + nx * GH_ + 4);

    // cvt current B to fp16 fragments
    half8 bf0, bf1;
    bf0[0] = (_Float16)b0a.x; bf0[1] = (_Float16)b0a.y;
    bf0[2] = (_Float16)b0a.z; bf0[3] = (_Float16)b0a.w;
    bf0[4] = (_Float16)b0b.x; bf0[5] = (_Float16)b0b.y;
    bf0[6] = (_Float16)b0b.z; bf0[7] = (_Float16)b0b.w;
    bf1[0] = (_Float16)b1a.x; bf1[1] = (_Float16)b1a.y;
    bf1[2] = (_Float16)b1a.z; bf1[3] = (_Float16)b1a.w;
    bf1[4] = (_Float16)b1b.x; bf1[5] = (_Float16)b1b.y;
    bf1[6] = (_Float16)b1b.z; bf1[7] = (_Float16)b1b.w;

    acc[0][0] = __builtin_amdgcn_mfma_f32_16x16x32_f16(a0, bf0, acc[0][0], 0, 0, 0);
    acc[1][0] = __builtin_amdgcn_mfma_f32_16x16x32_f16(a1, bf0, acc[1][0], 0, 0, 0);
    acc[2][0] = __builtin_amdgcn_mfma_f32_16x16x32_f16(a2, bf0, acc[2][0], 0, 0, 0);
    acc[3][0] = __builtin_amdgcn_mfma_f32_16x16x32_f16(a3, bf0, acc[3][0], 0, 0, 0);
    acc[0][1] = __builtin_amdgcn_mfma_f32_16x16x32_f16(a0, bf1, acc[0][1], 0, 0, 0);
    acc[1][1] = __builtin_amdgcn_mfma_f32_16x16x32_f16(a1, bf1, acc[1][1], 0, 0, 0);
    acc[2][1] = __builtin_amdgcn_mfma_f32_16x16x32_f16(a2, bf1, acc[2][1], 0, 0, 0);
    acc[3][1] = __builtin_amdgcn_mfma_f32_16x16x32_f16(a3, bf1, acc[3][1], 0, 0, 0);

    b0a = p0a; b0b = p0b; b1a = p1a; b1b = p1b;
    Ap += (size_t)BT_ * GH_;   // 8192 elems
  }

  // epilogue: C/D layout col=i16 (gate), row=q*4+r (bt within 16-tile)
#pragma unroll
  for (int mt = 0; mt < 4; ++mt) {
    const int bt = wv * 64 + mt * 16 + q * 4;
#pragma unroll
    for (int nt = 0; nt < 2; ++nt) {
      const int j = jn0 + nt * 16 + i16;
      if (use_atomic) {
#pragma unroll
        for (int r = 0; r < 4; ++r) atomicAdd(&pre_gates[(bt + r) * G4_ + j], acc[mt][nt][r]);
      } else {
#pragma unroll
        for (int r = 0; r < 4; ++r)
          partial[((size_t)kc * BT_ + (bt + r)) * G4_ + j] = acc[mt][nt][r];
      }
    }
  }
}

// ---------------------------------------------------------------------------
// K5: reduce split-K partials -> pre_gates.
// ---------------------------------------------------------------------------
__global__ __launch_bounds__(256) void reduce_kernel(
    const float* __restrict__ partial, float* __restrict__ pre_gates)
{
  const int o = blockIdx.x * 256 + threadIdx.x;
  float s0 = 0.f, s1 = 0.f;
  int kc = 0;
  for (; kc + 2 <= KC2_; kc += 2) {
    s0 += partial[(size_t)(kc + 0) * 65536 + o];
    s1 += partial[(size_t)(kc + 1) * 65536 + o];
  }
  for (; kc < KC2_; ++kc) s0 += partial[(size_t)kc * 65536 + o];
  pre_gates[o] = s0 + s1;
}

// ---------------------------------------------------------------------------
// K6: LSTM recurrence + head (fused). One block per batch b.
// ---------------------------------------------------------------------------
__global__ __launch_bounds__(256) void lstm_head_kernel(
    const float* __restrict__ pre_gates, const float* __restrict__ W_hh,
    const float* __restrict__ b_ih, const float* __restrict__ b_hh,
    const float* __restrict__ W_head, const float* __restrict__ b_head,
    float* __restrict__ out)
{
  const int b   = blockIdx.x;
  const int tid = threadIdx.x;
  __shared__ float h_s[H_];
  __shared__ float g_s[G4_];

  float wr[H_];
#pragma unroll
  for (int k = 0; k < H_; ++k) wr[k] = W_hh[(size_t)tid * H_ + k];

  float pg[S_];
#pragma unroll
  for (int t = 0; t < S_; ++t) pg[t] = pre_gates[(size_t)(b * S_ + t) * G4_ + tid];

  const float bias = b_ih[tid] + b_hh[tid];
  if (tid < H_) h_s[tid] = 0.f;
  float c = 0.f;
  __syncthreads();

  for (int t = 0; t < S_; ++t) {
    float g0 = pg[t] + bias, g1 = 0.f, g2 = 0.f, g3 = 0.f;
#pragma unroll
    for (int k = 0; k < H_; k += 4) {
      g0 = fmaf(wr[k + 0], h_s[k + 0], g0);
      g1 = fmaf(wr[k + 1], h_s[k + 1], g1);
      g2 = fmaf(wr[k + 2], h_s[k + 2], g2);
      g3 = fmaf(wr[k + 3], h_s[k + 3], g3);
    }
    g_s[tid] = (g0 + g1) + (g2 + g3);
    __syncthreads();
    if (tid < H_) {
      const float ig = fsigmoid(g_s[tid]);
      const float fg = fsigmoid(g_s[H_ + tid]);
      const float gg = ftanh_(g_s[2 * H_ + tid]);
      const float og = fsigmoid(g_s[3 * H_ + tid]);
      c = fg * c + ig * gg;
      h_s[tid] = og * ftanh_(c);
    }
    __syncthreads();
  }

  // head: out[b][n] = b_head[n] + sum_h h_s[h] * W_head[n][h]
  for (int n = tid; n < N_; n += 256) {
    const float4* w4 = (const float4*)(W_head + (size_t)n * H_);
    float acc = b_head[n];
#pragma unroll
    for (int qq = 0; qq < H_ / 4; ++qq) {
      const float4 w = w4[qq];
      acc += w.x * h_s[qq * 4 + 0] + w.y * h_s[qq * 4 + 1] +
             w.z * h_s[qq * 4 + 2] + w.w * h_s[qq * 4 + 3];
    }
    out[(size_t)b * N_ + n] = acc;
  }
}

// ---------------------------------------------------------------------------
extern "C" void kernel_launch(void* const* d_in, const int* in_sizes, int n_in,
                              void* d_out, int out_size, void* d_ws, size_t ws_size,
                              hipStream_t stream) {
  const float* x        = (const float*)d_in[0];
  const int*   ei       = (const int*)  d_in[1];
  const float* w_lin    = (const float*)d_in[2];
  const float* att_src  = (const float*)d_in[3];
  const float* att_dst  = (const float*)d_in[4];
  const float* gat_bias = (const float*)d_in[5];
  const float* W_ih     = (const float*)d_in[6];
  const float* W_hh     = (const float*)d_in[7];
  const float* b_ih     = (const float*)d_in[8];
  const float* b_hh     = (const float*)d_in[9];
  const float* W_head   = (const float*)d_in[10];
  const float* b_head   = (const float*)d_in[11];
  float* out = (float*)d_out;

  char* ws = (char*)d_ws;
  float*     xT        = (float*)    (ws + 0);           //  2,048,000
  _Float16*  A         = (_Float16*) (ws + 2048000);     // 32,768,000
  float*     pre_gates = (float*)    (ws + 34816000);    //    262,144
  int*       rowptr    = (int*)      (ws + 35078144);    //      8,192
  int*       csr_src   = (int*)      (ws + 35086336);    //    256,000
  float*     partial   = (float*)    (ws + 35342336);    // 50*65536*4 = 13,107,200
  const size_t need = 35342336 + (size_t)KC2_ * 65536 * sizeof(float);  // ~48.4 MB
  const int use_atomic = (ws_size < need) ? 1 : 0;

  csr_build_kernel<<<dim3(1), dim3(1024), 0, stream>>>(ei, rowptr, csr_src);
  transpose_kernel<<<dim3((N_ + 31) / 32, BT_ / 32), dim3(256), 0, stream>>>(x, xT);
  gat_gather_expand_kernel<<<dim3(N_), dim3(256), 0, stream>>>(
      xT, rowptr, csr_src, w_lin, att_src, att_dst, gat_bias, A);

  if (use_atomic) {
    hipMemsetAsync(pre_gates, 0, G4_ * BT_ * sizeof(float), stream);
  }
  gate_mfma2_kernel<<<dim3(8, KC2_), dim3(256), 0, stream>>>(
      W_ih, A, partial, pre_gates, use_atomic);
  if (!use_atomic) {
    reduce_kernel<<<dim3(256), dim3(256), 0, stream>>>(partial, pre_gates);
  }

  lstm_head_kernel<<<dim3(B_), dim3(256), 0, stream>>>(
      pre_gates, W_hh, b_ih, b_hh, W_head, b_head, out);
}